// Round 11
// baseline (121.327 us; speedup 1.0000x reference)
//
#include <hip/hip_runtime.h>

// Problem constants
#define B_SZ    4096
#define DD      256
#define T_TREES 64
#define NNODES  21
#define S_LEAF  64
#define M_SUP   512                         // rows per block (4 tiles of 128)
#define HBYTES  40960                       // one k-half (160 cols x 128 k x 2B)
#define WBYTES  (2 * HBYTES)                // 81920 B per tree
#define XOFF    ((size_t)T_TREES * WBYTES)  // bf16 input offset in ws
#define QBYTES  20480                       // (fallback kernel only)

// Column order (per tree): c = n*4+w for nodes n<=4 (cols 0..19); pad 20..31;
// leaf nodes n>=5 at c = 32+s for leaf s; preds at 96+s.

typedef __attribute__((ext_vector_type(8))) short  short8;
typedef __attribute__((ext_vector_type(4))) float  f32x4;

// DPP cross-lane (VALU pipe, zero DS cost)
#define DPP_ADD(x, ctrl) ((x) + __int_as_float(__builtin_amdgcn_mov_dpp(__float_as_int(x), (ctrl), 0xF, 0xF, true)))
#define DPP_MOV(x, ctrl) __int_as_float(__builtin_amdgcn_mov_dpp(__float_as_int(x), (ctrl), 0xF, 0xF, true))
__device__ __forceinline__ float qsum4(float x) {   // sum over aligned quad
    x = DPP_ADD(x, 0xB1);
    x = DPP_ADD(x, 0x4E);
    return x;
}
__device__ __forceinline__ float rsum16(float x) {  // sum over aligned 16-lane row
    x = DPP_ADD(x, 0xB1);
    x = DPP_ADD(x, 0x4E);
    x = DPP_ADD(x, 0x124);
    x = DPP_ADD(x, 0x128);
    return x;
}

__device__ __forceinline__ unsigned short f2bf(float f) {
    unsigned int u = __float_as_uint(f);
    u += 0x7fffu + ((u >> 16) & 1u);
    return (unsigned short)(u >> 16);
}
__device__ __forceinline__ void gl2lds16(const void* g, void* l) {
    __builtin_amdgcn_global_load_lds(
        (const __attribute__((address_space(1))) unsigned int*)g,
        (__attribute__((address_space(3))) unsigned int*)l, 16, 0, 0);
}
// swizzled 16B-chunk offset within one 40960B k-half: col c (0..159), klo (0..15)
__device__ __host__ __forceinline__ int woffh(int c, int klo) {
    return c * 256 + (((klo ^ c) & 15) << 4);
}
// fallback quarter layout (klo 0..7)
__device__ __host__ __forceinline__ int woffq(int c, int klo) {
    return (c >> 1) * 256 + (((((klo << 1) ^ (c & 14))) | (c & 1)) << 4);
}

__global__ void zero_ave_kernel(float* __restrict__ out1) {
    int i = blockIdx.x * 256 + threadIdx.x;
    if (i < B_SZ) out1[i] = 0.0f;
}

// ---------------- pre-pass ----------------
// ws: [0, 64*WBYTES) bf16 swizzled weights (half layout); [XOFF, +2MB) bf16 inputs
// id ranges: Wn [0,43008) | pad [43008,67584) | pred [67584,198656)
//            out1-zero [198656,202752) | input-cvt [202752,333824)
__global__ void prep_weights(const float* __restrict__ Wn, const float* __restrict__ W0,
                             const float* __restrict__ W1, const float* __restrict__ inp0,
                             const float* __restrict__ inp1, char* __restrict__ ws,
                             float* __restrict__ out1) {
    int id = blockIdx.x * 256 + threadIdx.x;
    if (id < 43008) {
        int oct  = id & 31;               // global k-chunk 0..31
        int rest = id >> 5;               // t*21+n
        int n    = rest % NNODES;
        int t    = rest / NNODES;
        int h    = oct >> 4, klo = oct & 15;
        const f32x4* src = (const f32x4*)(Wn + (((size_t)t * NNODES + n) * DD + oct * 8) * 4);
        f32x4 v[8];
        #pragma unroll
        for (int j = 0; j < 8; ++j) v[j] = src[j];
        char* base = ws + (size_t)t * WBYTES + h * HBYTES;
        #pragma unroll
        for (int w = 0; w < 4; ++w) {
            int c = n * 4 + w + (n >= 5 ? 12 : 0);
            short8 pack;
            #pragma unroll
            for (int j = 0; j < 8; ++j) pack[j] = (short)f2bf(v[j][w]);
            *(short8*)(base + woffh(c, klo)) = pack;
        }
    } else if (id < 67584) {
        int idx  = id - 43008;
        int kc   = idx & 31;
        int rest = idx >> 5;
        int c    = 20 + rest % 12;
        int t    = rest / 12;
        short8 z = (short8){0,0,0,0,0,0,0,0};
        *(short8*)(ws + (size_t)t * WBYTES + (kc >> 4) * HBYTES + woffh(c, kc & 15)) = z;
    } else if (id < 198656) {
        int idx = id - 67584;
        int kc  = idx & 31;
        int s   = (idx >> 5) & 63;
        int t   = idx >> 11;
        int k0  = kc * 8;
        const float* src = (k0 < 128) ? (W0 + ((size_t)t * S_LEAF + s) * 128 + k0)
                                      : (W1 + ((size_t)t * S_LEAF + s) * 128 + (k0 - 128));
        short8 pack;
        #pragma unroll
        for (int j = 0; j < 8; ++j) pack[j] = (short)f2bf(src[j]);
        *(short8*)(ws + (size_t)t * WBYTES + (kc >> 4) * HBYTES + woffh(96 + s, kc & 15)) = pack;
    } else if (id < 202752) {
        out1[id - 198656] = 0.0f;
    } else if (id < 333824) {
        int idx = id - 202752;
        int oct = idx & 31;
        int r   = idx >> 5;
        const float* src = (oct < 16) ? (inp0 + (size_t)r * 128 + oct * 8)
                                      : (inp1 + (size_t)r * 128 + (oct - 16) * 8);
        f32x4 f0 = *(const f32x4*)src;
        f32x4 f1 = *(const f32x4*)(src + 4);
        short8 pack;
        pack[0]=(short)f2bf(f0[0]); pack[1]=(short)f2bf(f0[1]);
        pack[2]=(short)f2bf(f0[2]); pack[3]=(short)f2bf(f0[3]);
        pack[4]=(short)f2bf(f1[0]); pack[5]=(short)f2bf(f1[1]);
        pack[6]=(short)f2bf(f1[2]); pack[7]=(short)f2bf(f1[3]);
        *(short8*)(ws + XOFF + ((size_t)r * DD + oct * 8) * 2) = pack;
    }
}

// ---------------- main kernel: 1 tree x 512 rows per block, stage once, 1 barrier ----------------
__global__ __launch_bounds__(256, 2)
void forest_main(const float* __restrict__ x2,  const float* __restrict__ bn,
                 const float* __restrict__ b0,  const float* __restrict__ b1,
                 const char* __restrict__ wsW,
                 float* __restrict__ out0, float* __restrict__ out1) {
    __shared__ __align__(16) char smem[WBYTES];   // 81920 B: both k-halves resident

    const int tid  = threadIdx.x;
    const int orig = blockIdx.x;                 // 512 = 8 XCDs * 64
    const int swz  = (orig & 7) * 64 + (orig >> 3);
    const int t    = swz >> 3;                   // tree (8 per XCD)
    const int st   = swz & 7;                    // row supertile
    const int m0   = st * M_SUP;
    const int lane = tid & 63;
    const int wid  = tid >> 6;
    const int ri   = lane & 15;
    const int kg   = lane >> 4;

    const unsigned short* xbf = (const unsigned short*)(wsW + XOFF);
    const char* wbase = wsW + (size_t)t * WBYTES;

    // stage the ENTIRE tree (80 KB) once: linear async DMA
    {
        const char* src = wbase + tid * 16;
        char* dst = smem + tid * 16;
        #pragma unroll
        for (int it = 0; it < 20; ++it)
            gl2lds16(src + it * 4096, dst + it * 4096);
    }
    __syncthreads();   // the ONLY barrier; weights resident for the whole block

    const int kgbase = kg * 16;

    for (int rt = 0; rt < 4; ++rt) {
        const int r0 = m0 + rt * 128;
        const int gr0r = r0 + wid * 32 + ri;     // strip-0 row
        const int gr1r = gr0r + 16;              // strip-1 row

        f32x4 acc[2][10];
        #pragma unroll
        for (int sr = 0; sr < 2; ++sr)
            #pragma unroll
            for (int ct = 0; ct < 10; ++ct)
                acc[sr][ct] = (f32x4){0.f, 0.f, 0.f, 0.f};

        #pragma unroll
        for (int kk = 0; kk < 8; ++kk) {
            short8 a0 = *(const short8*)(xbf + (size_t)gr0r * DD + kk * 32 + kg * 8);
            short8 a1 = *(const short8*)(xbf + (size_t)gr1r * DD + kk * 32 + kg * 8);
            const int klo = (kk & 3) * 4 + kg;
            const int dsB = (kk >> 2) * HBYTES + ri * 256 + (((klo ^ ri) & 15) << 4);
            #pragma unroll
            for (int ct = 0; ct < 10; ++ct) {
                short8 bv = *(const short8*)(smem + dsB + ct * 4096);
                acc[0][ct] = __builtin_amdgcn_mfma_f32_16x16x32_bf16(a0, bv, acc[0][ct], 0, 0, 0);
                acc[1][ct] = __builtin_amdgcn_mfma_f32_16x16x32_bf16(a1, bv, acc[1][ct], 0, 0, 0);
            }
        }

        // epilogue (register-resident, DPP sums, fused leaf+pred) — R8 verified
        #pragma unroll
        for (int sr = 0; sr < 2; ++sr) {
            const int gr0 = r0 + wid * 32 + sr * 16 + kg * 4;
            f32x4 x2v = *(const f32x4*)(x2 + gr0);
            float bn0 = bn[t * 84 + ri];                    // cols 0..15 (nodes 0..3)
            float bn1 = bn[t * 84 + 16 + (ri & 3)];         // node4 bias (valid lanes ri<4)

            float L1r[4];
            #pragma unroll
            for (int r = 0; r < 4; ++r) {
                float e0 = __expf(acc[sr][0][r] + bn0);
                float p0 = e0 * __builtin_amdgcn_rcpf(qsum4(e0));
                float e1 = __expf(acc[sr][1][r] + bn1);
                float p1 = e1 * __builtin_amdgcn_rcpf(qsum4(e1));
                float pa  = __shfl(p0, kgbase + (ri >> 2));   // P0[j>>2]
                float pb0 = DPP_MOV(p0, 0x124);               // lane j <- (j+4)%16
                float pb1 = DPP_MOV(p1, 0x124);
                L1r[r] = pa * ((ri < 12) ? pb0 : pb1);
            }
            float partial[4] = {0.f, 0.f, 0.f, 0.f};
            #pragma unroll
            for (int ct = 0; ct < 4; ++ct) {
                int s = ct * 16 + ri;
                float bn2 = bn[t * 84 + 20 + s];
                float bb  = b0[t * S_LEAF + s] + b1[t * S_LEAF + s];
                #pragma unroll
                for (int r = 0; r < 4; ++r) {
                    float e = __expf(acc[sr][2 + ct][r] + bn2);
                    float p2 = e * __builtin_amdgcn_rcpf(qsum4(e));
                    float L2 = p2 * __shfl(L1r[r], kgbase + ct * 4 + (ri >> 2));
                    float y = acc[sr][6 + ct][r] + x2v[r] + bb;
                    out0[((size_t)(gr0 + r) * T_TREES + t) * S_LEAF + s] = y;
                    float sg = __builtin_amdgcn_rcpf(1.0f + __expf(-y));
                    partial[r] += sg * L2;
                }
            }
            #pragma unroll
            for (int r = 0; r < 4; ++r) {
                float p = rsum16(partial[r]);
                if (ri == 0) atomicAdd(out1 + gr0 + r, p * (1.0f / T_TREES));
            }
        }
    }
}

// ---------------- fallback (no workspace): R8 verified path ----------------
__device__ __forceinline__ short8 ldAraw(const float* __restrict__ inp0,
                                         const float* __restrict__ inp1,
                                         int gr, int kkidx, int kg) {
    int k0 = kkidx * 32 + kg * 8;
    const float* src = (k0 < 128) ? (inp0 + (size_t)gr * 128 + k0)
                                  : (inp1 + (size_t)gr * 128 + (k0 - 128));
    f32x4 f0 = *(const f32x4*)src;
    f32x4 f1 = *(const f32x4*)(src + 4);
    short8 a;
    a[0]=(short)f2bf(f0[0]); a[1]=(short)f2bf(f0[1]);
    a[2]=(short)f2bf(f0[2]); a[3]=(short)f2bf(f0[3]);
    a[4]=(short)f2bf(f1[0]); a[5]=(short)f2bf(f1[1]);
    a[6]=(short)f2bf(f1[2]); a[7]=(short)f2bf(f1[3]);
    return a;
}

__global__ __launch_bounds__(256, 2)
void forest_fb(const float* __restrict__ inp0, const float* __restrict__ inp1,
               const float* __restrict__ x2,   const float* __restrict__ Wn,
               const float* __restrict__ bn,   const float* __restrict__ W0,
               const float* __restrict__ b0,   const float* __restrict__ W1,
               const float* __restrict__ b1,
               float* __restrict__ out0, float* __restrict__ out1) {
    __shared__ __align__(16) char smem[QBYTES];

    const int tid  = threadIdx.x;
    const int orig = blockIdx.x;                 // 2048
    const int swz  = (orig & 7) * 256 + (orig >> 3);
    const int t    = swz >> 5;
    const int mt   = swz & 31;
    const int m0   = mt * 128;
    const int lane = tid & 63;
    const int wid  = tid >> 6;
    const int ri   = lane & 15;
    const int kg   = lane >> 4;

    f32x4 acc[2][10];
    #pragma unroll
    for (int sr = 0; sr < 2; ++sr)
        #pragma unroll
        for (int ct = 0; ct < 10; ++ct)
            acc[sr][ct] = (f32x4){0.f, 0.f, 0.f, 0.f};

    const int gr0r = m0 + wid * 32 + ri;
    const int gr1r = gr0r + 16;

    int dsb[2];
    #pragma unroll
    for (int kkl = 0; kkl < 2; ++kkl) {
        int klo = kkl * 4 + kg;
        dsb[kkl] = (ri >> 1) * 256 + (((((klo << 1) ^ (ri & 14))) | (ri & 1)) << 4);
    }

    for (int q = 0; q < 4; ++q) {
        #pragma unroll
        for (int it = 0; it < 5; ++it) {
            int idx = tid + it * 256;
            int c   = idx >> 3;
            int klo = idx & 7;
            int k0  = (q * 8 + klo) * 8;
            unsigned short v[8];
            if (c < 20) {
                int n = c >> 2, w = c & 3;
                const float* src = Wn + (((size_t)t * NNODES + n) * DD + k0) * 4 + w;
                #pragma unroll
                for (int j = 0; j < 8; ++j) v[j] = f2bf(src[j * 4]);
            } else if (c < 32) {
                #pragma unroll
                for (int j = 0; j < 8; ++j) v[j] = 0;
            } else if (c < 96) {
                int n = 5 + ((c - 32) >> 2), w = (c - 32) & 3;
                const float* src = Wn + (((size_t)t * NNODES + n) * DD + k0) * 4 + w;
                #pragma unroll
                for (int j = 0; j < 8; ++j) v[j] = f2bf(src[j * 4]);
            } else {
                int s = c - 96;
                const float* src = (k0 < 128) ? (W0 + ((size_t)t * S_LEAF + s) * 128 + k0)
                                              : (W1 + ((size_t)t * S_LEAF + s) * 128 + (k0 - 128));
                #pragma unroll
                for (int j = 0; j < 8; ++j) v[j] = f2bf(src[j]);
            }
            short8 pack;
            #pragma unroll
            for (int j = 0; j < 8; ++j) pack[j] = (short)v[j];
            *(short8*)(smem + woffq(c, klo)) = pack;
        }
        short8 a00 = ldAraw(inp0, inp1, gr0r, 2*q+0, kg);
        short8 a10 = ldAraw(inp0, inp1, gr1r, 2*q+0, kg);
        short8 a01 = ldAraw(inp0, inp1, gr0r, 2*q+1, kg);
        short8 a11 = ldAraw(inp0, inp1, gr1r, 2*q+1, kg);
        __syncthreads();
        #pragma unroll
        for (int ct = 0; ct < 10; ++ct) {
            short8 b0f = *(const short8*)(smem + dsb[0] + ct * 2048);
            acc[0][ct] = __builtin_amdgcn_mfma_f32_16x16x32_bf16(a00, b0f, acc[0][ct], 0, 0, 0);
            acc[1][ct] = __builtin_amdgcn_mfma_f32_16x16x32_bf16(a10, b0f, acc[1][ct], 0, 0, 0);
        }
        #pragma unroll
        for (int ct = 0; ct < 10; ++ct) {
            short8 b1f = *(const short8*)(smem + dsb[1] + ct * 2048);
            acc[0][ct] = __builtin_amdgcn_mfma_f32_16x16x32_bf16(a01, b1f, acc[0][ct], 0, 0, 0);
            acc[1][ct] = __builtin_amdgcn_mfma_f32_16x16x32_bf16(a11, b1f, acc[1][ct], 0, 0, 0);
        }
        if (q < 3) __syncthreads();
    }

    const int kgbase = kg * 16;
    #pragma unroll
    for (int sr = 0; sr < 2; ++sr) {
        const int rlBase = wid * 32 + sr * 16 + kg * 4;
        const int gr0 = m0 + rlBase;
        f32x4 x2v = *(const f32x4*)(x2 + gr0);
        float bn0 = bn[t * 84 + ri];
        float bn1 = bn[t * 84 + 16 + (ri & 3)];
        float L1r[4];
        #pragma unroll
        for (int r = 0; r < 4; ++r) {
            float e0 = __expf(acc[sr][0][r] + bn0);
            float p0 = e0 * __builtin_amdgcn_rcpf(qsum4(e0));
            float e1 = __expf(acc[sr][1][r] + bn1);
            float p1 = e1 * __builtin_amdgcn_rcpf(qsum4(e1));
            float pa  = __shfl(p0, kgbase + (ri >> 2));
            float pb0 = DPP_MOV(p0, 0x124);
            float pb1 = DPP_MOV(p1, 0x124);
            L1r[r] = pa * ((ri < 12) ? pb0 : pb1);
        }
        float partial[4] = {0.f, 0.f, 0.f, 0.f};
        #pragma unroll
        for (int ct = 0; ct < 4; ++ct) {
            int s = ct * 16 + ri;
            float bn2 = bn[t * 84 + 20 + s];
            float bb  = b0[t * S_LEAF + s] + b1[t * S_LEAF + s];
            #pragma unroll
            for (int r = 0; r < 4; ++r) {
                float e = __expf(acc[sr][2 + ct][r] + bn2);
                float p2 = e * __builtin_amdgcn_rcpf(qsum4(e));
                float L2 = p2 * __shfl(L1r[r], kgbase + ct * 4 + (ri >> 2));
                float y = acc[sr][6 + ct][r] + x2v[r] + bb;
                out0[((size_t)(gr0 + r) * T_TREES + t) * S_LEAF + s] = y;
                float sg = __builtin_amdgcn_rcpf(1.0f + __expf(-y));
                partial[r] += sg * L2;
            }
        }
        #pragma unroll
        for (int r = 0; r < 4; ++r) {
            float p = rsum16(partial[r]);
            if (ri == 0) atomicAdd(out1 + gr0 + r, p * (1.0f / T_TREES));
        }
    }
}

extern "C" void kernel_launch(void* const* d_in, const int* in_sizes, int n_in,
                              void* d_out, int out_size, void* d_ws, size_t ws_size,
                              hipStream_t stream) {
    const float* inp0 = (const float*)d_in[0];
    const float* inp1 = (const float*)d_in[1];
    const float* x2   = (const float*)d_in[2];
    const float* Wn   = (const float*)d_in[3];
    const float* bn   = (const float*)d_in[4];
    const float* W0   = (const float*)d_in[5];
    const float* b0   = (const float*)d_in[6];
    const float* W1   = (const float*)d_in[7];
    const float* b1   = (const float*)d_in[8];

    float* out0 = (float*)d_out;
    float* out1 = out0 + (size_t)B_SZ * T_TREES * S_LEAF;

    const size_t need = XOFF + (size_t)B_SZ * DD * 2;   // 5.25 MB + 2 MB

    if (ws_size >= need) {
        hipLaunchKernelGGL(prep_weights, dim3(1304), dim3(256), 0, stream,
                           Wn, W0, W1, inp0, inp1, (char*)d_ws, out1);
        hipLaunchKernelGGL(forest_main, dim3((B_SZ / M_SUP) * T_TREES), dim3(256), 0, stream,
                           x2, bn, b0, b1, (const char*)d_ws, out0, out1);
    } else {
        hipLaunchKernelGGL(zero_ave_kernel, dim3((B_SZ + 255) / 256), dim3(256), 0, stream, out1);
        hipLaunchKernelGGL(forest_fb, dim3((B_SZ / 128) * T_TREES), dim3(256), 0, stream,
                           inp0, inp1, x2, Wn, bn, W0, b0, W1, b1, out0, out1);
    }
}

// Round 12
// 51.862 us; speedup vs baseline: 2.3394x; 2.3394x over previous
//
#include <hip/hip_runtime.h>

// Problem constants
#define B_SZ    4096
#define DD      256
#define T_TREES 64
#define NNODES  21
#define S_LEAF  64
#define M_TILE  128                         // rows per block (32 per wave, 2 strips)
#define HBYTES  40960                       // one k-half (160 cols x 128 k x 2B)
#define WBYTES  (2 * HBYTES)                // 81920 B per tree
#define XOFF    ((size_t)T_TREES * WBYTES)  // bf16 input offset in ws
#define QBYTES  20480                       // (fallback kernel only)

// Column order (per tree): c = n*4+w for nodes n<=4 (cols 0..19); pad 20..31;
// leaf nodes n>=5 at c = 32+s for leaf s; preds at 96+s.

typedef __attribute__((ext_vector_type(8))) short  short8;
typedef __attribute__((ext_vector_type(4))) float  f32x4;

// DPP cross-lane (VALU pipe, zero DS cost)
#define DPP_ADD(x, ctrl) ((x) + __int_as_float(__builtin_amdgcn_mov_dpp(__float_as_int(x), (ctrl), 0xF, 0xF, true)))
#define DPP_MOV(x, ctrl) __int_as_float(__builtin_amdgcn_mov_dpp(__float_as_int(x), (ctrl), 0xF, 0xF, true))
__device__ __forceinline__ float qsum4(float x) {   // sum over aligned quad
    x = DPP_ADD(x, 0xB1);
    x = DPP_ADD(x, 0x4E);
    return x;
}
__device__ __forceinline__ float rsum16(float x) {  // sum over aligned 16-lane row
    x = DPP_ADD(x, 0xB1);
    x = DPP_ADD(x, 0x4E);
    x = DPP_ADD(x, 0x124);
    x = DPP_ADD(x, 0x128);
    return x;
}

__device__ __forceinline__ unsigned short f2bf(float f) {
    unsigned int u = __float_as_uint(f);
    u += 0x7fffu + ((u >> 16) & 1u);
    return (unsigned short)(u >> 16);
}
__device__ __forceinline__ void gl2lds16(const void* g, void* l) {
    __builtin_amdgcn_global_load_lds(
        (const __attribute__((address_space(1))) unsigned int*)g,
        (__attribute__((address_space(3))) unsigned int*)l, 16, 0, 0);
}
// swizzled 16B-chunk offset within one 40960B k-half: col c (0..159), klo (0..15)
__device__ __host__ __forceinline__ int woffh(int c, int klo) {
    return c * 256 + (((klo ^ c) & 15) << 4);
}
// fallback quarter layout (klo 0..7)
__device__ __host__ __forceinline__ int woffq(int c, int klo) {
    return (c >> 1) * 256 + (((((klo << 1) ^ (c & 14))) | (c & 1)) << 4);
}

__global__ void zero_ave_kernel(float* __restrict__ out1) {
    int i = blockIdx.x * 256 + threadIdx.x;
    if (i < B_SZ) out1[i] = 0.0f;
}

// ---------------- pre-pass ----------------
// ws: [0, 64*WBYTES) bf16 swizzled weights (half layout); [XOFF, +2MB) bf16 inputs
// id ranges: Wn [0,43008) | pad [43008,67584) | pred [67584,198656)
//            out1-zero [198656,202752) | input-cvt [202752,333824)
__global__ void prep_weights(const float* __restrict__ Wn, const float* __restrict__ W0,
                             const float* __restrict__ W1, const float* __restrict__ inp0,
                             const float* __restrict__ inp1, char* __restrict__ ws,
                             float* __restrict__ out1) {
    int id = blockIdx.x * 256 + threadIdx.x;
    if (id < 43008) {
        int oct  = id & 31;               // global k-chunk 0..31
        int rest = id >> 5;               // t*21+n
        int n    = rest % NNODES;
        int t    = rest / NNODES;
        int h    = oct >> 4, klo = oct & 15;
        const f32x4* src = (const f32x4*)(Wn + (((size_t)t * NNODES + n) * DD + oct * 8) * 4);
        f32x4 v[8];
        #pragma unroll
        for (int j = 0; j < 8; ++j) v[j] = src[j];
        char* base = ws + (size_t)t * WBYTES + h * HBYTES;
        #pragma unroll
        for (int w = 0; w < 4; ++w) {
            int c = n * 4 + w + (n >= 5 ? 12 : 0);
            short8 pack;
            #pragma unroll
            for (int j = 0; j < 8; ++j) pack[j] = (short)f2bf(v[j][w]);
            *(short8*)(base + woffh(c, klo)) = pack;
        }
    } else if (id < 67584) {
        int idx  = id - 43008;
        int kc   = idx & 31;
        int rest = idx >> 5;
        int c    = 20 + rest % 12;
        int t    = rest / 12;
        short8 z = (short8){0,0,0,0,0,0,0,0};
        *(short8*)(ws + (size_t)t * WBYTES + (kc >> 4) * HBYTES + woffh(c, kc & 15)) = z;
    } else if (id < 198656) {
        int idx = id - 67584;
        int kc  = idx & 31;
        int s   = (idx >> 5) & 63;
        int t   = idx >> 11;
        int k0  = kc * 8;
        const float* src = (k0 < 128) ? (W0 + ((size_t)t * S_LEAF + s) * 128 + k0)
                                      : (W1 + ((size_t)t * S_LEAF + s) * 128 + (k0 - 128));
        short8 pack;
        #pragma unroll
        for (int j = 0; j < 8; ++j) pack[j] = (short)f2bf(src[j]);
        *(short8*)(ws + (size_t)t * WBYTES + (kc >> 4) * HBYTES + woffh(96 + s, kc & 15)) = pack;
    } else if (id < 202752) {
        out1[id - 198656] = 0.0f;
    } else if (id < 333824) {
        int idx = id - 202752;
        int oct = idx & 31;
        int r   = idx >> 5;
        const float* src = (oct < 16) ? (inp0 + (size_t)r * 128 + oct * 8)
                                      : (inp1 + (size_t)r * 128 + (oct - 16) * 8);
        f32x4 f0 = *(const f32x4*)src;
        f32x4 f1 = *(const f32x4*)(src + 4);
        short8 pack;
        pack[0]=(short)f2bf(f0[0]); pack[1]=(short)f2bf(f0[1]);
        pack[2]=(short)f2bf(f0[2]); pack[3]=(short)f2bf(f0[3]);
        pack[4]=(short)f2bf(f1[0]); pack[5]=(short)f2bf(f1[1]);
        pack[6]=(short)f2bf(f1[2]); pack[7]=(short)f2bf(f1[3]);
        *(short8*)(ws + XOFF + ((size_t)r * DD + oct * 8) * 2) = pack;
    }
}

// ---------------- main kernel: R8 skeleton + no reg cap + A-prefetch ----------------
__global__ __launch_bounds__(256, 2)
void forest_main(const float* __restrict__ x2,  const float* __restrict__ bn,
                 const float* __restrict__ b0,  const float* __restrict__ b1,
                 const char* __restrict__ wsW,
                 float* __restrict__ out0, float* __restrict__ out1) {
    __shared__ __align__(16) char smem[HBYTES];   // 40960 B, single buffer

    const int tid  = threadIdx.x;
    const int orig = blockIdx.x;                 // 2048 = 8 XCDs * 256
    const int swz  = (orig & 7) * 256 + (orig >> 3);
    const int t    = swz >> 5;                   // tree (8 per XCD)
    const int mt   = swz & 31;                   // row tile
    const int m0   = mt * M_TILE;
    const int lane = tid & 63;
    const int wid  = tid >> 6;
    const int ri   = lane & 15;
    const int kg   = lane >> 4;

    const unsigned short* xbf = (const unsigned short*)(wsW + XOFF);
    const char* wbase = wsW + (size_t)t * WBYTES;

    f32x4 acc[2][10];
    #pragma unroll
    for (int sr = 0; sr < 2; ++sr)
        #pragma unroll
        for (int ct = 0; ct < 10; ++ct)
            acc[sr][ct] = (f32x4){0.f, 0.f, 0.f, 0.f};

    const int gr0r = m0 + wid * 32 + ri;         // strip-0 row
    const int gr1r = gr0r + 16;                  // strip-1 row
    const unsigned short* aBase0 = xbf + (size_t)gr0r * DD + kg * 8;
    const unsigned short* aBase1 = xbf + (size_t)gr1r * DD + kg * 8;

    for (int h = 0; h < 2; ++h) {
        // stage half h: 40 KB linear async DMA
        {
            const char* src = wbase + h * HBYTES + tid * 16;
            char* dst = smem + tid * 16;
            #pragma unroll
            for (int it = 0; it < 10; ++it)
                gl2lds16(src + it * 4096, dst + it * 4096);
        }
        // prefetch first A pair of this half under the DMA (drained by same barrier)
        short8 a0 = *(const short8*)(aBase0 + (h * 4) * 32);
        short8 a1 = *(const short8*)(aBase1 + (h * 4) * 32);
        __syncthreads();   // DMA + A(0) drained, buffer ready

        #pragma unroll
        for (int ks = 0; ks < 4; ++ks) {
            short8 n0, n1;
            if (ks < 3) {   // prefetch next A pair; latency hidden under 20 MFMAs
                n0 = *(const short8*)(aBase0 + (h * 4 + ks + 1) * 32);
                n1 = *(const short8*)(aBase1 + (h * 4 + ks + 1) * 32);
            }
            const int klo = ks * 4 + kg;
            const int dsB = ri * 256 + (((klo ^ ri) & 15) << 4);
            #pragma unroll
            for (int ct = 0; ct < 10; ++ct) {
                short8 bv = *(const short8*)(smem + dsB + ct * 4096);
                acc[0][ct] = __builtin_amdgcn_mfma_f32_16x16x32_bf16(a0, bv, acc[0][ct], 0, 0, 0);
                acc[1][ct] = __builtin_amdgcn_mfma_f32_16x16x32_bf16(a1, bv, acc[1][ct], 0, 0, 0);
            }
            a0 = n0; a1 = n1;
        }
        if (h == 0) __syncthreads();   // all waves done reading before restage
    }
    // no barrier after last half: epilogue uses no LDS

    // ---------------- epilogue (register-resident, DPP sums, fused leaf+pred) ----------------
    const int kgbase = kg * 16;
    #pragma unroll
    for (int sr = 0; sr < 2; ++sr) {
        const int rlBase = wid * 32 + sr * 16 + kg * 4;
        const int gr0 = m0 + rlBase;
        f32x4 x2v = *(const f32x4*)(x2 + gr0);
        float bn0 = bn[t * 84 + ri];                    // cols 0..15 (nodes 0..3)
        float bn1 = bn[t * 84 + 16 + (ri & 3)];         // node4 bias (valid lanes ri<4)

        // levels 0/1 -> L1 per lane (lane j holds L1[j])
        float L1r[4];
        #pragma unroll
        for (int r = 0; r < 4; ++r) {
            float e0 = __expf(acc[sr][0][r] + bn0);
            float p0 = e0 * __builtin_amdgcn_rcpf(qsum4(e0));
            float e1 = __expf(acc[sr][1][r] + bn1);
            float p1 = e1 * __builtin_amdgcn_rcpf(qsum4(e1));
            float pa  = __shfl(p0, kgbase + (ri >> 2));   // P0[j>>2]
            float pb0 = DPP_MOV(p0, 0x124);               // lane j <- (j+4)%16
            float pb1 = DPP_MOV(p1, 0x124);
            L1r[r] = pa * ((ri < 12) ? pb0 : pb1);
        }
        // fused leaf softmax + pred + weighted reduce (s = ct*16 + ri)
        float partial[4] = {0.f, 0.f, 0.f, 0.f};
        #pragma unroll
        for (int ct = 0; ct < 4; ++ct) {
            int s = ct * 16 + ri;
            float bn2 = bn[t * 84 + 20 + s];
            float bb  = b0[t * S_LEAF + s] + b1[t * S_LEAF + s];
            #pragma unroll
            for (int r = 0; r < 4; ++r) {
                float e = __expf(acc[sr][2 + ct][r] + bn2);
                float p2 = e * __builtin_amdgcn_rcpf(qsum4(e));
                float L2 = p2 * __shfl(L1r[r], kgbase + ct * 4 + (ri >> 2));
                float y = acc[sr][6 + ct][r] + x2v[r] + bb;
                out0[((size_t)(gr0 + r) * T_TREES + t) * S_LEAF + s] = y;
                float sg = __builtin_amdgcn_rcpf(1.0f + __expf(-y));
                partial[r] += sg * L2;
            }
        }
        #pragma unroll
        for (int r = 0; r < 4; ++r) {
            float p = rsum16(partial[r]);
            if (ri == 0) atomicAdd(out1 + gr0 + r, p * (1.0f / T_TREES));
        }
    }
}

// ---------------- fallback (no workspace): in-kernel staging path ----------------
__device__ __forceinline__ short8 ldAraw(const float* __restrict__ inp0,
                                         const float* __restrict__ inp1,
                                         int gr, int kkidx, int kg) {
    int k0 = kkidx * 32 + kg * 8;
    const float* src = (k0 < 128) ? (inp0 + (size_t)gr * 128 + k0)
                                  : (inp1 + (size_t)gr * 128 + (k0 - 128));
    f32x4 f0 = *(const f32x4*)src;
    f32x4 f1 = *(const f32x4*)(src + 4);
    short8 a;
    a[0]=(short)f2bf(f0[0]); a[1]=(short)f2bf(f0[1]);
    a[2]=(short)f2bf(f0[2]); a[3]=(short)f2bf(f0[3]);
    a[4]=(short)f2bf(f1[0]); a[5]=(short)f2bf(f1[1]);
    a[6]=(short)f2bf(f1[2]); a[7]=(short)f2bf(f1[3]);
    return a;
}

__global__ __launch_bounds__(256, 2)
void forest_fb(const float* __restrict__ inp0, const float* __restrict__ inp1,
               const float* __restrict__ x2,   const float* __restrict__ Wn,
               const float* __restrict__ bn,   const float* __restrict__ W0,
               const float* __restrict__ b0,   const float* __restrict__ W1,
               const float* __restrict__ b1,
               float* __restrict__ out0, float* __restrict__ out1) {
    __shared__ __align__(16) char smem[QBYTES];

    const int tid  = threadIdx.x;
    const int orig = blockIdx.x;                 // 2048
    const int swz  = (orig & 7) * 256 + (orig >> 3);
    const int t    = swz >> 5;
    const int mt   = swz & 31;
    const int m0   = mt * 128;
    const int lane = tid & 63;
    const int wid  = tid >> 6;
    const int ri   = lane & 15;
    const int kg   = lane >> 4;

    f32x4 acc[2][10];
    #pragma unroll
    for (int sr = 0; sr < 2; ++sr)
        #pragma unroll
        for (int ct = 0; ct < 10; ++ct)
            acc[sr][ct] = (f32x4){0.f, 0.f, 0.f, 0.f};

    const int gr0r = m0 + wid * 32 + ri;
    const int gr1r = gr0r + 16;

    int dsb[2];
    #pragma unroll
    for (int kkl = 0; kkl < 2; ++kkl) {
        int klo = kkl * 4 + kg;
        dsb[kkl] = (ri >> 1) * 256 + (((((klo << 1) ^ (ri & 14))) | (ri & 1)) << 4);
    }

    for (int q = 0; q < 4; ++q) {
        #pragma unroll
        for (int it = 0; it < 5; ++it) {
            int idx = tid + it * 256;
            int c   = idx >> 3;
            int klo = idx & 7;
            int k0  = (q * 8 + klo) * 8;
            unsigned short v[8];
            if (c < 20) {
                int n = c >> 2, w = c & 3;
                const float* src = Wn + (((size_t)t * NNODES + n) * DD + k0) * 4 + w;
                #pragma unroll
                for (int j = 0; j < 8; ++j) v[j] = f2bf(src[j * 4]);
            } else if (c < 32) {
                #pragma unroll
                for (int j = 0; j < 8; ++j) v[j] = 0;
            } else if (c < 96) {
                int n = 5 + ((c - 32) >> 2), w = (c - 32) & 3;
                const float* src = Wn + (((size_t)t * NNODES + n) * DD + k0) * 4 + w;
                #pragma unroll
                for (int j = 0; j < 8; ++j) v[j] = f2bf(src[j * 4]);
            } else {
                int s = c - 96;
                const float* src = (k0 < 128) ? (W0 + ((size_t)t * S_LEAF + s) * 128 + k0)
                                              : (W1 + ((size_t)t * S_LEAF + s) * 128 + (k0 - 128));
                #pragma unroll
                for (int j = 0; j < 8; ++j) v[j] = f2bf(src[j]);
            }
            short8 pack;
            #pragma unroll
            for (int j = 0; j < 8; ++j) pack[j] = (short)v[j];
            *(short8*)(smem + woffq(c, klo)) = pack;
        }
        short8 a00 = ldAraw(inp0, inp1, gr0r, 2*q+0, kg);
        short8 a10 = ldAraw(inp0, inp1, gr1r, 2*q+0, kg);
        short8 a01 = ldAraw(inp0, inp1, gr0r, 2*q+1, kg);
        short8 a11 = ldAraw(inp0, inp1, gr1r, 2*q+1, kg);
        __syncthreads();
        #pragma unroll
        for (int ct = 0; ct < 10; ++ct) {
            short8 b0f = *(const short8*)(smem + dsb[0] + ct * 2048);
            acc[0][ct] = __builtin_amdgcn_mfma_f32_16x16x32_bf16(a00, b0f, acc[0][ct], 0, 0, 0);
            acc[1][ct] = __builtin_amdgcn_mfma_f32_16x16x32_bf16(a10, b0f, acc[1][ct], 0, 0, 0);
        }
        #pragma unroll
        for (int ct = 0; ct < 10; ++ct) {
            short8 b1f = *(const short8*)(smem + dsb[1] + ct * 2048);
            acc[0][ct] = __builtin_amdgcn_mfma_f32_16x16x32_bf16(a01, b1f, acc[0][ct], 0, 0, 0);
            acc[1][ct] = __builtin_amdgcn_mfma_f32_16x16x32_bf16(a11, b1f, acc[1][ct], 0, 0, 0);
        }
        if (q < 3) __syncthreads();
    }

    const int kgbase = kg * 16;
    #pragma unroll
    for (int sr = 0; sr < 2; ++sr) {
        const int rlBase = wid * 32 + sr * 16 + kg * 4;
        const int gr0 = m0 + rlBase;
        f32x4 x2v = *(const f32x4*)(x2 + gr0);
        float bn0 = bn[t * 84 + ri];
        float bn1 = bn[t * 84 + 16 + (ri & 3)];
        float L1r[4];
        #pragma unroll
        for (int r = 0; r < 4; ++r) {
            float e0 = __expf(acc[sr][0][r] + bn0);
            float p0 = e0 * __builtin_amdgcn_rcpf(qsum4(e0));
            float e1 = __expf(acc[sr][1][r] + bn1);
            float p1 = e1 * __builtin_amdgcn_rcpf(qsum4(e1));
            float pa  = __shfl(p0, kgbase + (ri >> 2));
            float pb0 = DPP_MOV(p0, 0x124);
            float pb1 = DPP_MOV(p1, 0x124);
            L1r[r] = pa * ((ri < 12) ? pb0 : pb1);
        }
        float partial[4] = {0.f, 0.f, 0.f, 0.f};
        #pragma unroll
        for (int ct = 0; ct < 4; ++ct) {
            int s = ct * 16 + ri;
            float bn2 = bn[t * 84 + 20 + s];
            float bb  = b0[t * S_LEAF + s] + b1[t * S_LEAF + s];
            #pragma unroll
            for (int r = 0; r < 4; ++r) {
                float e = __expf(acc[sr][2 + ct][r] + bn2);
                float p2 = e * __builtin_amdgcn_rcpf(qsum4(e));
                float L2 = p2 * __shfl(L1r[r], kgbase + ct * 4 + (ri >> 2));
                float y = acc[sr][6 + ct][r] + x2v[r] + bb;
                out0[((size_t)(gr0 + r) * T_TREES + t) * S_LEAF + s] = y;
                float sg = __builtin_amdgcn_rcpf(1.0f + __expf(-y));
                partial[r] += sg * L2;
            }
        }
        #pragma unroll
        for (int r = 0; r < 4; ++r) {
            float p = rsum16(partial[r]);
            if (ri == 0) atomicAdd(out1 + gr0 + r, p * (1.0f / T_TREES));
        }
    }
}

extern "C" void kernel_launch(void* const* d_in, const int* in_sizes, int n_in,
                              void* d_out, int out_size, void* d_ws, size_t ws_size,
                              hipStream_t stream) {
    const float* inp0 = (const float*)d_in[0];
    const float* inp1 = (const float*)d_in[1];
    const float* x2   = (const float*)d_in[2];
    const float* Wn   = (const float*)d_in[3];
    const float* bn   = (const float*)d_in[4];
    const float* W0   = (const float*)d_in[5];
    const float* b0   = (const float*)d_in[6];
    const float* W1   = (const float*)d_in[7];
    const float* b1   = (const float*)d_in[8];

    float* out0 = (float*)d_out;
    float* out1 = out0 + (size_t)B_SZ * T_TREES * S_LEAF;

    const size_t need = XOFF + (size_t)B_SZ * DD * 2;   // 5.25 MB + 2 MB
    dim3 grid((B_SZ / M_TILE) * T_TREES);               // 2048

    if (ws_size >= need) {
        hipLaunchKernelGGL(prep_weights, dim3(1304), dim3(256), 0, stream,
                           Wn, W0, W1, inp0, inp1, (char*)d_ws, out1);
        hipLaunchKernelGGL(forest_main, grid, dim3(256), 0, stream,
                           x2, bn, b0, b1, (const char*)d_ws, out0, out1);
    } else {
        hipLaunchKernelGGL(zero_ave_kernel, dim3((B_SZ + 255) / 256), dim3(256), 0, stream, out1);
        hipLaunchKernelGGL(forest_fb, grid, dim3(256), 0, stream,
                           inp0, inp1, x2, Wn, bn, W0, b0, W1, b1, out0, out1);
    }
}

// Round 13
// 48.138 us; speedup vs baseline: 2.5204x; 1.0774x over previous
//
#include <hip/hip_runtime.h>

// Problem constants
#define B_SZ    4096
#define DD      256
#define T_TREES 64
#define NNODES  21
#define S_LEAF  64
#define M_TILE  128                         // rows per block (16 per wave, 8 waves)
#define HBYTES  40960                       // one k-half (160 cols x 128 k x 2B)
#define WBYTES  (2 * HBYTES)                // 81920 B per tree
#define XOFF    ((size_t)T_TREES * WBYTES)  // bf16 input offset in ws
#define QBYTES  20480                       // (fallback kernel only)

// Column order (per tree): c = n*4+w for nodes n<=4 (cols 0..19); pad 20..31;
// leaf nodes n>=5 at c = 32+s for leaf s; preds at 96+s.

typedef __attribute__((ext_vector_type(8))) short  short8;
typedef __attribute__((ext_vector_type(4))) float  f32x4;

// DPP cross-lane (VALU pipe, zero DS cost)
#define DPP_ADD(x, ctrl) ((x) + __int_as_float(__builtin_amdgcn_mov_dpp(__float_as_int(x), (ctrl), 0xF, 0xF, true)))
#define DPP_MOV(x, ctrl) __int_as_float(__builtin_amdgcn_mov_dpp(__float_as_int(x), (ctrl), 0xF, 0xF, true))
__device__ __forceinline__ float qsum4(float x) {   // sum over aligned quad
    x = DPP_ADD(x, 0xB1);
    x = DPP_ADD(x, 0x4E);
    return x;
}
__device__ __forceinline__ float rsum16(float x) {  // sum over aligned 16-lane row
    x = DPP_ADD(x, 0xB1);
    x = DPP_ADD(x, 0x4E);
    x = DPP_ADD(x, 0x124);
    x = DPP_ADD(x, 0x128);
    return x;
}

__device__ __forceinline__ unsigned short f2bf(float f) {
    unsigned int u = __float_as_uint(f);
    u += 0x7fffu + ((u >> 16) & 1u);
    return (unsigned short)(u >> 16);
}
__device__ __forceinline__ void gl2lds16(const void* g, void* l) {
    __builtin_amdgcn_global_load_lds(
        (const __attribute__((address_space(1))) unsigned int*)g,
        (__attribute__((address_space(3))) unsigned int*)l, 16, 0, 0);
}
// swizzled 16B-chunk offset within one 40960B k-half: col c (0..159), klo (0..15)
__device__ __host__ __forceinline__ int woffh(int c, int klo) {
    return c * 256 + (((klo ^ c) & 15) << 4);
}
// fallback quarter layout (klo 0..7)
__device__ __host__ __forceinline__ int woffq(int c, int klo) {
    return (c >> 1) * 256 + (((((klo << 1) ^ (c & 14))) | (c & 1)) << 4);
}

__global__ void zero_ave_kernel(float* __restrict__ out1) {
    int i = blockIdx.x * 256 + threadIdx.x;
    if (i < B_SZ) out1[i] = 0.0f;
}

// ---------------- pre-pass ----------------
// ws: [0, 64*WBYTES) bf16 swizzled weights (half layout); [XOFF, +2MB) bf16 inputs
// id ranges: Wn [0,43008) | pad [43008,67584) | pred [67584,198656)
//            out1-zero [198656,202752) | input-cvt [202752,333824)
__global__ void prep_weights(const float* __restrict__ Wn, const float* __restrict__ W0,
                             const float* __restrict__ W1, const float* __restrict__ inp0,
                             const float* __restrict__ inp1, char* __restrict__ ws,
                             float* __restrict__ out1) {
    int id = blockIdx.x * 256 + threadIdx.x;
    if (id < 43008) {
        int oct  = id & 31;               // global k-chunk 0..31
        int rest = id >> 5;               // t*21+n
        int n    = rest % NNODES;
        int t    = rest / NNODES;
        int h    = oct >> 4, klo = oct & 15;
        const f32x4* src = (const f32x4*)(Wn + (((size_t)t * NNODES + n) * DD + oct * 8) * 4);
        f32x4 v[8];
        #pragma unroll
        for (int j = 0; j < 8; ++j) v[j] = src[j];
        char* base = ws + (size_t)t * WBYTES + h * HBYTES;
        #pragma unroll
        for (int w = 0; w < 4; ++w) {
            int c = n * 4 + w + (n >= 5 ? 12 : 0);
            short8 pack;
            #pragma unroll
            for (int j = 0; j < 8; ++j) pack[j] = (short)f2bf(v[j][w]);
            *(short8*)(base + woffh(c, klo)) = pack;
        }
    } else if (id < 67584) {
        int idx  = id - 43008;
        int kc   = idx & 31;
        int rest = idx >> 5;
        int c    = 20 + rest % 12;
        int t    = rest / 12;
        short8 z = (short8){0,0,0,0,0,0,0,0};
        *(short8*)(ws + (size_t)t * WBYTES + (kc >> 4) * HBYTES + woffh(c, kc & 15)) = z;
    } else if (id < 198656) {
        int idx = id - 67584;
        int kc  = idx & 31;
        int s   = (idx >> 5) & 63;
        int t   = idx >> 11;
        int k0  = kc * 8;
        const float* src = (k0 < 128) ? (W0 + ((size_t)t * S_LEAF + s) * 128 + k0)
                                      : (W1 + ((size_t)t * S_LEAF + s) * 128 + (k0 - 128));
        short8 pack;
        #pragma unroll
        for (int j = 0; j < 8; ++j) pack[j] = (short)f2bf(src[j]);
        *(short8*)(ws + (size_t)t * WBYTES + (kc >> 4) * HBYTES + woffh(96 + s, kc & 15)) = pack;
    } else if (id < 202752) {
        out1[id - 198656] = 0.0f;
    } else if (id < 333824) {
        int idx = id - 202752;
        int oct = idx & 31;
        int r   = idx >> 5;
        const float* src = (oct < 16) ? (inp0 + (size_t)r * 128 + oct * 8)
                                      : (inp1 + (size_t)r * 128 + (oct - 16) * 8);
        f32x4 f0 = *(const f32x4*)src;
        f32x4 f1 = *(const f32x4*)(src + 4);
        short8 pack;
        pack[0]=(short)f2bf(f0[0]); pack[1]=(short)f2bf(f0[1]);
        pack[2]=(short)f2bf(f0[2]); pack[3]=(short)f2bf(f0[3]);
        pack[4]=(short)f2bf(f1[0]); pack[5]=(short)f2bf(f1[1]);
        pack[6]=(short)f2bf(f1[2]); pack[7]=(short)f2bf(f1[3]);
        *(short8*)(ws + XOFF + ((size_t)r * DD + oct * 8) * 2) = pack;
    }
}

// ---------------- main kernel: 512 thr, 8 waves x 16 rows, acc=40, reg-only epilogue ----------------
__global__ __launch_bounds__(512, 4)
void forest_main(const float* __restrict__ x2,  const float* __restrict__ bn,
                 const float* __restrict__ b0,  const float* __restrict__ b1,
                 const char* __restrict__ wsW,
                 float* __restrict__ out0, float* __restrict__ out1) {
    __shared__ __align__(16) char smem[HBYTES];   // 40960 B, single buffer

    const int tid  = threadIdx.x;
    const int orig = blockIdx.x;                 // 2048 = 8 XCDs * 256
    const int swz  = (orig & 7) * 256 + (orig >> 3);
    const int t    = swz >> 5;                   // tree (8 per XCD)
    const int mt   = swz & 31;                   // row tile
    const int m0   = mt * M_TILE;
    const int lane = tid & 63;
    const int wid  = tid >> 6;                   // 0..7
    const int ri   = lane & 15;
    const int kg   = lane >> 4;

    const unsigned short* xbf = (const unsigned short*)(wsW + XOFF);
    const char* wbase = wsW + (size_t)t * WBYTES;

    f32x4 acc[10];
    #pragma unroll
    for (int ct = 0; ct < 10; ++ct)
        acc[ct] = (f32x4){0.f, 0.f, 0.f, 0.f};

    const int grr = m0 + wid * 16 + ri;          // this lane's A row
    const unsigned short* aBase = xbf + (size_t)grr * DD + kg * 8;

    for (int h = 0; h < 2; ++h) {
        // stage half h: 40 KB linear async DMA (512 thr x 16B x 5)
        {
            const char* src = wbase + h * HBYTES + tid * 16;
            char* dst = smem + tid * 16;
            #pragma unroll
            for (int it = 0; it < 5; ++it)
                gl2lds16(src + it * 8192, dst + it * 8192);
        }
        // prefetch first A of this half under the DMA (drained by same barrier)
        short8 a = *(const short8*)(aBase + (h * 4) * 32);
        __syncthreads();   // DMA + A(0) drained, buffer ready

        #pragma unroll
        for (int ks = 0; ks < 4; ++ks) {
            short8 an;
            if (ks < 3)    // prefetch next A; latency hidden under 10 MFMAs
                an = *(const short8*)(aBase + (h * 4 + ks + 1) * 32);
            const int klo = ks * 4 + kg;
            const int dsB = ri * 256 + (((klo ^ ri) & 15) << 4);
            #pragma unroll
            for (int ct = 0; ct < 10; ++ct) {
                short8 bv = *(const short8*)(smem + dsB + ct * 4096);
                acc[ct] = __builtin_amdgcn_mfma_f32_16x16x32_bf16(a, bv, acc[ct], 0, 0, 0);
            }
            a = an;
        }
        if (h == 0) __syncthreads();   // all waves done reading before restage
    }
    // no barrier after last half: epilogue uses no LDS

    // ---------------- epilogue (register-resident, DPP sums, fused leaf+pred) ----------------
    const int kgbase = kg * 16;
    {
        const int rlBase = wid * 16 + kg * 4;
        const int gr0 = m0 + rlBase;
        f32x4 x2v = *(const f32x4*)(x2 + gr0);
        float bn0 = bn[t * 84 + ri];                    // cols 0..15 (nodes 0..3)
        float bn1 = bn[t * 84 + 16 + (ri & 3)];         // node4 bias (valid lanes ri<4)

        // levels 0/1 -> L1 per lane (lane j holds L1[j])
        float L1r[4];
        #pragma unroll
        for (int r = 0; r < 4; ++r) {
            float e0 = __expf(acc[0][r] + bn0);
            float p0 = e0 * __builtin_amdgcn_rcpf(qsum4(e0));
            float e1 = __expf(acc[1][r] + bn1);
            float p1 = e1 * __builtin_amdgcn_rcpf(qsum4(e1));
            float pa  = __shfl(p0, kgbase + (ri >> 2));   // P0[j>>2]
            float pb0 = DPP_MOV(p0, 0x124);               // lane j <- (j+4)%16
            float pb1 = DPP_MOV(p1, 0x124);
            L1r[r] = pa * ((ri < 12) ? pb0 : pb1);
        }
        // fused leaf softmax + pred + weighted reduce (s = ct*16 + ri)
        float partial[4] = {0.f, 0.f, 0.f, 0.f};
        #pragma unroll
        for (int ct = 0; ct < 4; ++ct) {
            int s = ct * 16 + ri;
            float bn2 = bn[t * 84 + 20 + s];
            float bb  = b0[t * S_LEAF + s] + b1[t * S_LEAF + s];
            #pragma unroll
            for (int r = 0; r < 4; ++r) {
                float e = __expf(acc[2 + ct][r] + bn2);
                float p2 = e * __builtin_amdgcn_rcpf(qsum4(e));
                float L2 = p2 * __shfl(L1r[r], kgbase + ct * 4 + (ri >> 2));
                float y = acc[6 + ct][r] + x2v[r] + bb;
                out0[((size_t)(gr0 + r) * T_TREES + t) * S_LEAF + s] = y;
                float sg = __builtin_amdgcn_rcpf(1.0f + __expf(-y));
                partial[r] += sg * L2;
            }
        }
        #pragma unroll
        for (int r = 0; r < 4; ++r) {
            float p = rsum16(partial[r]);
            if (ri == 0) atomicAdd(out1 + gr0 + r, p * (1.0f / T_TREES));
        }
    }
}

// ---------------- fallback (no workspace): in-kernel staging path ----------------
__device__ __forceinline__ short8 ldAraw(const float* __restrict__ inp0,
                                         const float* __restrict__ inp1,
                                         int gr, int kkidx, int kg) {
    int k0 = kkidx * 32 + kg * 8;
    const float* src = (k0 < 128) ? (inp0 + (size_t)gr * 128 + k0)
                                  : (inp1 + (size_t)gr * 128 + (k0 - 128));
    f32x4 f0 = *(const f32x4*)src;
    f32x4 f1 = *(const f32x4*)(src + 4);
    short8 a;
    a[0]=(short)f2bf(f0[0]); a[1]=(short)f2bf(f0[1]);
    a[2]=(short)f2bf(f0[2]); a[3]=(short)f2bf(f0[3]);
    a[4]=(short)f2bf(f1[0]); a[5]=(short)f2bf(f1[1]);
    a[6]=(short)f2bf(f1[2]); a[7]=(short)f2bf(f1[3]);
    return a;
}

__global__ __launch_bounds__(256, 2)
void forest_fb(const float* __restrict__ inp0, const float* __restrict__ inp1,
               const float* __restrict__ x2,   const float* __restrict__ Wn,
               const float* __restrict__ bn,   const float* __restrict__ W0,
               const float* __restrict__ b0,   const float* __restrict__ W1,
               const float* __restrict__ b1,
               float* __restrict__ out0, float* __restrict__ out1) {
    __shared__ __align__(16) char smem[QBYTES];

    const int tid  = threadIdx.x;
    const int orig = blockIdx.x;                 // 2048
    const int swz  = (orig & 7) * 256 + (orig >> 3);
    const int t    = swz >> 5;
    const int mt   = swz & 31;
    const int m0   = mt * 128;
    const int lane = tid & 63;
    const int wid  = tid >> 6;
    const int ri   = lane & 15;
    const int kg   = lane >> 4;

    f32x4 acc[2][10];
    #pragma unroll
    for (int sr = 0; sr < 2; ++sr)
        #pragma unroll
        for (int ct = 0; ct < 10; ++ct)
            acc[sr][ct] = (f32x4){0.f, 0.f, 0.f, 0.f};

    const int gr0r = m0 + wid * 32 + ri;
    const int gr1r = gr0r + 16;

    int dsb[2];
    #pragma unroll
    for (int kkl = 0; kkl < 2; ++kkl) {
        int klo = kkl * 4 + kg;
        dsb[kkl] = (ri >> 1) * 256 + (((((klo << 1) ^ (ri & 14))) | (ri & 1)) << 4);
    }

    for (int q = 0; q < 4; ++q) {
        #pragma unroll
        for (int it = 0; it < 5; ++it) {
            int idx = tid + it * 256;
            int c   = idx >> 3;
            int klo = idx & 7;
            int k0  = (q * 8 + klo) * 8;
            unsigned short v[8];
            if (c < 20) {
                int n = c >> 2, w = c & 3;
                const float* src = Wn + (((size_t)t * NNODES + n) * DD + k0) * 4 + w;
                #pragma unroll
                for (int j = 0; j < 8; ++j) v[j] = f2bf(src[j * 4]);
            } else if (c < 32) {
                #pragma unroll
                for (int j = 0; j < 8; ++j) v[j] = 0;
            } else if (c < 96) {
                int n = 5 + ((c - 32) >> 2), w = (c - 32) & 3;
                const float* src = Wn + (((size_t)t * NNODES + n) * DD + k0) * 4 + w;
                #pragma unroll
                for (int j = 0; j < 8; ++j) v[j] = f2bf(src[j * 4]);
            } else {
                int s = c - 96;
                const float* src = (k0 < 128) ? (W0 + ((size_t)t * S_LEAF + s) * 128 + k0)
                                              : (W1 + ((size_t)t * S_LEAF + s) * 128 + (k0 - 128));
                #pragma unroll
                for (int j = 0; j < 8; ++j) v[j] = f2bf(src[j]);
            }
            short8 pack;
            #pragma unroll
            for (int j = 0; j < 8; ++j) pack[j] = (short)v[j];
            *(short8*)(smem + woffq(c, klo)) = pack;
        }
        short8 a00 = ldAraw(inp0, inp1, gr0r, 2*q+0, kg);
        short8 a10 = ldAraw(inp0, inp1, gr1r, 2*q+0, kg);
        short8 a01 = ldAraw(inp0, inp1, gr0r, 2*q+1, kg);
        short8 a11 = ldAraw(inp0, inp1, gr1r, 2*q+1, kg);
        __syncthreads();
        #pragma unroll
        for (int ct = 0; ct < 10; ++ct) {
            short8 b0f = *(const short8*)(smem + dsb[0] + ct * 2048);
            acc[0][ct] = __builtin_amdgcn_mfma_f32_16x16x32_bf16(a00, b0f, acc[0][ct], 0, 0, 0);
            acc[1][ct] = __builtin_amdgcn_mfma_f32_16x16x32_bf16(a10, b0f, acc[1][ct], 0, 0, 0);
        }
        #pragma unroll
        for (int ct = 0; ct < 10; ++ct) {
            short8 b1f = *(const short8*)(smem + dsb[1] + ct * 2048);
            acc[0][ct] = __builtin_amdgcn_mfma_f32_16x16x32_bf16(a01, b1f, acc[0][ct], 0, 0, 0);
            acc[1][ct] = __builtin_amdgcn_mfma_f32_16x16x32_bf16(a11, b1f, acc[1][ct], 0, 0, 0);
        }
        if (q < 3) __syncthreads();
    }

    const int kgbase = kg * 16;
    #pragma unroll
    for (int sr = 0; sr < 2; ++sr) {
        const int rlBase = wid * 32 + sr * 16 + kg * 4;
        const int gr0 = m0 + rlBase;
        f32x4 x2v = *(const f32x4*)(x2 + gr0);
        float bn0 = bn[t * 84 + ri];
        float bn1 = bn[t * 84 + 16 + (ri & 3)];
        float L1r[4];
        #pragma unroll
        for (int r = 0; r < 4; ++r) {
            float e0 = __expf(acc[sr][0][r] + bn0);
            float p0 = e0 * __builtin_amdgcn_rcpf(qsum4(e0));
            float e1 = __expf(acc[sr][1][r] + bn1);
            float p1 = e1 * __builtin_amdgcn_rcpf(qsum4(e1));
            float pa  = __shfl(p0, kgbase + (ri >> 2));
            float pb0 = DPP_MOV(p0, 0x124);
            float pb1 = DPP_MOV(p1, 0x124);
            L1r[r] = pa * ((ri < 12) ? pb0 : pb1);
        }
        float partial[4] = {0.f, 0.f, 0.f, 0.f};
        #pragma unroll
        for (int ct = 0; ct < 4; ++ct) {
            int s = ct * 16 + ri;
            float bn2 = bn[t * 84 + 20 + s];
            float bb  = b0[t * S_LEAF + s] + b1[t * S_LEAF + s];
            #pragma unroll
            for (int r = 0; r < 4; ++r) {
                float e = __expf(acc[sr][2 + ct][r] + bn2);
                float p2 = e * __builtin_amdgcn_rcpf(qsum4(e));
                float L2 = p2 * __shfl(L1r[r], kgbase + ct * 4 + (ri >> 2));
                float y = acc[sr][6 + ct][r] + x2v[r] + bb;
                out0[((size_t)(gr0 + r) * T_TREES + t) * S_LEAF + s] = y;
                float sg = __builtin_amdgcn_rcpf(1.0f + __expf(-y));
                partial[r] += sg * L2;
            }
        }
        #pragma unroll
        for (int r = 0; r < 4; ++r) {
            float p = rsum16(partial[r]);
            if (ri == 0) atomicAdd(out1 + gr0 + r, p * (1.0f / T_TREES));
        }
    }
}

extern "C" void kernel_launch(void* const* d_in, const int* in_sizes, int n_in,
                              void* d_out, int out_size, void* d_ws, size_t ws_size,
                              hipStream_t stream) {
    const float* inp0 = (const float*)d_in[0];
    const float* inp1 = (const float*)d_in[1];
    const float* x2   = (const float*)d_in[2];
    const float* Wn   = (const float*)d_in[3];
    const float* bn   = (const float*)d_in[4];
    const float* W0   = (const float*)d_in[5];
    const float* b0   = (const float*)d_in[6];
    const float* W1   = (const float*)d_in[7];
    const float* b1   = (const float*)d_in[8];

    float* out0 = (float*)d_out;
    float* out1 = out0 + (size_t)B_SZ * T_TREES * S_LEAF;

    const size_t need = XOFF + (size_t)B_SZ * DD * 2;   // 5.25 MB + 2 MB
    dim3 grid((B_SZ / M_TILE) * T_TREES);               // 2048

    if (ws_size >= need) {
        hipLaunchKernelGGL(prep_weights, dim3(1304), dim3(256), 0, stream,
                           Wn, W0, W1, inp0, inp1, (char*)d_ws, out1);
        hipLaunchKernelGGL(forest_main, grid, dim3(512), 0, stream,
                           x2, bn, b0, b1, (const char*)d_ws, out0, out1);
    } else {
        hipLaunchKernelGGL(zero_ave_kernel, dim3((B_SZ + 255) / 256), dim3(256), 0, stream, out1);
        hipLaunchKernelGGL(forest_fb, grid, dim3(256), 0, stream,
                           inp0, inp1, x2, Wn, bn, W0, b0, W1, b1, out0, out1);
    }
}